// Round 2
// baseline (243.337 us; speedup 1.0000x reference)
//
#include <hip/hip_runtime.h>

// RGCN_70566312673746: out[e,o] = xsum[e] * sum_r (1/cs[e,r]) * Wsum[r,o]
//   Wsum[r,o] = sum_i W[r,i,o].  E=100000, R=64, I=256, O=256.
//   edge_index is UNUSED by the reference output.
//
// Round-4 structure (R3 post-mortem: all three app kernels ran < 61.7 us each
// (absent from rocprof top-5, which was all 409.6MB harness poison fills), yet
// dur_us=232 vs a ~39 us data-motion roofline. Controllable defects: K3 had
// 3.05 tiles/wave (33% tail imbalance) and ~220 VGPR (128-VGPR W-frag hoist)
// -> 2 waves/SIMD; K1/K2 serialized though independent):
//   K1 pre_kernel: FUSED Wsum^T + xsum. Blocks [0,256) reduce W -> bf16
//      Wsum^T[o][r] (identical indexing to verified R3 wsum_kernel, 1024 thr).
//      Blocks [256,768) compute row sums of x (16 waves/block, 8192 waves,
//      same wave code as verified R3 xsum_kernel). The 16.8MB W pass now
//      overlaps the 102.4MB x pass instead of serializing.
//   K2 out_kernel: ONE 16-row e-tile per wave (6250 waves, perfect balance,
//      straight-line, no grid-stride/prefetch state). W^T frags are re-read
//      per-tile from wsumT (32KB -> L1/L2 resident) instead of hoisted into
//      128 VGPRs; __launch_bounds__(256,4) caps VGPR at 128 -> 4 waves/SIMD
//      for 2x the latency hiding. MFMA mapping (D[o][e], A=W^T, B=recip)
//      and bf16 numerics byte-identical to the harness-verified R3 kernel.
//
// (Round-1 resubmission: previous bench attempt died on GPUAcquisitionTimeout
// — no signal received; kernel unchanged.)

constexpr int En = 100000;
constexpr int Rn = 64;
constexpr int In = 256;
constexpr int On = 256;
constexpr int TILES = En / 16;   // 6250, exact (no row guards needed in K2)

constexpr int WSUM_BLOCKS = 256; // r = b>>2, o-quarter h = b&3
constexpr int XSUM_BLOCKS = 512; // 16 waves/block -> 8192 waves

typedef short bf16x8 __attribute__((ext_vector_type(8)));
typedef float floatx4 __attribute__((ext_vector_type(4)));

// round-to-nearest-even fp32 -> bf16 bits (finite values only)
static __device__ __forceinline__ short f2bf(float f) {
    unsigned u = __builtin_bit_cast(unsigned, f);
    unsigned r = (u + 0x7FFFu + ((u >> 16) & 1u)) >> 16;
    return (short)r;
}

// ---- K1: fused Wsum^T (blocks [0,256)) + xsum (blocks [256,768)). ----
__global__ __launch_bounds__(1024) void pre_kernel(const float* __restrict__ W,
                                                   const float* __restrict__ x,
                                                   short* __restrict__ wsumT,
                                                   float* __restrict__ xsum,
                                                   int xstride) {
    __shared__ float red[16][65];
    if (blockIdx.x < WSUM_BLOCKS) {
        // Wsum^T[o][r] = bf16(sum_i W[r,i,o]).  block b: r=b>>2, o-quarter h=b&3.
        // 1024 threads: o_local = t&63, i-chunk ic = t>>6 (16 i's each).
        const int r  = blockIdx.x >> 2;
        const int h  = blockIdx.x & 3;
        const int ol = threadIdx.x & 63;
        const int ic = threadIdx.x >> 6;
        const int o  = h * 64 + ol;
        const float* base = W + ((size_t)r * In + (size_t)ic * 16) * On + o;
        float s = 0.f;
#pragma unroll
        for (int i = 0; i < 16; ++i) s += base[(size_t)i * On];
        red[ic][ol] = s;
        __syncthreads();
        if (ic == 0) {
            float t = 0.f;
#pragma unroll
            for (int j = 0; j < 16; ++j) t += red[j][ol];
            wsumT[o * Rn + r] = f2bf(t);
        }
    } else {
        // xsum[e] = sum_j x[e,j].  Wave per row, 4 rows in flight.
        const int w    = ((int)(blockIdx.x - WSUM_BLOCKS) * 1024 + (int)threadIdx.x) >> 6;
        const int nw   = (XSUM_BLOCKS * 1024) >> 6;   // 8192
        const int lane = threadIdx.x & 63;
        for (int base = w * 4; base < En; base += nw * 4) {
            float s[4];
#pragma unroll
            for (int u = 0; u < 4; ++u) {
                const int row = base + u;
                float4 v = make_float4(0.f, 0.f, 0.f, 0.f);
                if (row < En)
                    v = *(const float4*)&x[(size_t)row * In + lane * 4];
                s[u] = (v.x + v.y) + (v.z + v.w);
            }
#pragma unroll
            for (int u = 0; u < 4; ++u) {
#pragma unroll
                for (int off = 32; off; off >>= 1) s[u] += __shfl_down(s[u], off, 64);
            }
            if (lane == 0) {
#pragma unroll
                for (int u = 0; u < 4; ++u)
                    if (base + u < En) xsum[(size_t)(base + u) * xstride] = s[u];
            }
        }
    }
}

// ---- K2: out rows.  ONE 16-e-row tile per wave (6250 waves), straight-line.
//      MFMA computes D[o][e] (A = W^T frags, B = recip frags):
//        lane (q = ln>>4, lm = ln&15): e = t*16+lm, o = ot*16 + q*4 + rg. ----
__global__ __launch_bounds__(256, 4) void out_kernel(const float* __restrict__ cs,
                                                     const short* __restrict__ wsumT,
                                                     const float* __restrict__ xsum,
                                                     int xstride,
                                                     float* __restrict__ out) {
    const int gw = (blockIdx.x * 256 + (int)threadIdx.x) >> 6;
    if (gw >= TILES) return;
    const int ln = threadIdx.x & 63;
    const int lm = ln & 15;
    const int q  = ln >> 4;
    const int e0 = gw * 16 + lm;

    // cs fragment sources + this row's xsum
    const float* p = cs + (size_t)e0 * Rn + q * 8;
    const float4 d0 = *(const float4*)p;
    const float4 d1 = *(const float4*)(p + 4);
    const float4 d2 = *(const float4*)(p + 32);
    const float4 d3 = *(const float4*)(p + 36);
    const float xs  = xsum[(size_t)e0 * xstride];

    // B frags: B[k=r=q*8+j][n=e_local=lm] = bf16(1/cs[e][r])
    bf16x8 b0, b1;
    {
        const float rv[16] = {d0.x, d0.y, d0.z, d0.w, d1.x, d1.y, d1.z, d1.w,
                              d2.x, d2.y, d2.z, d2.w, d3.x, d3.y, d3.z, d3.w};
#pragma unroll
        for (int j = 0; j < 8; ++j) {
            b0[j] = f2bf(__builtin_amdgcn_rcpf(rv[j]));
            b1[j] = f2bf(__builtin_amdgcn_rcpf(rv[8 + j]));
        }
    }

    float* orow = out + (size_t)e0 * On + q * 4;
    const short* wb = wsumT + lm * Rn + q * 8;   // A[m=o_local=lm][k=r=q*8+j]
#pragma unroll
    for (int ot = 0; ot < 16; ++ot) {
        const short* wp = wb + ot * 16 * Rn;
        const bf16x8 wa0 = *(const bf16x8*)wp;          // r = q*8 .. q*8+7
        const bf16x8 wa1 = *(const bf16x8*)(wp + 32);   // r = 32+q*8 ..
        floatx4 acc = {0.f, 0.f, 0.f, 0.f};
        acc = __builtin_amdgcn_mfma_f32_16x16x32_bf16(wa0, b0, acc, 0, 0, 0);
        acc = __builtin_amdgcn_mfma_f32_16x16x32_bf16(wa1, b1, acc, 0, 0, 0);
        // D: row=q*4+rg -> o, col=lm -> e; 4 consecutive o => float4 store
        const float4 st = make_float4(acc[0] * xs, acc[1] * xs,
                                      acc[2] * xs, acc[3] * xs);
        *(float4*)(orow + ot * 16) = st;
    }
}

extern "C" void kernel_launch(void* const* d_in, const int* in_sizes, int n_in,
                              void* d_out, int out_size, void* d_ws, size_t ws_size,
                              hipStream_t stream) {
    const float* x  = (const float*)d_in[0];   // (E, I) fp32
    const float* cs = (const float*)d_in[1];   // (E, R) fp32
    const float* W  = (const float*)d_in[2];   // (R, I, O) fp32
    // d_in[3] = edge_index: unused by the reference output.
    float* out = (float*)d_out;

    short* wsumT = (short*)d_ws;               // 32 KB bf16 [o][r]
    float* xsum;
    int xstride;
    if (ws_size >= (size_t)(32768 + En * 4)) {
        xsum = (float*)((char*)d_ws + 32768);  // 400 KB
        xstride = 1;
    } else {
        // Fallback: park xsum in out[:,0]; K2 reads it (each row read only by
        // the wave that later overwrites it, reads precede all its stores).
        xsum = out;
        xstride = On;
    }

    pre_kernel<<<dim3(WSUM_BLOCKS + XSUM_BLOCKS), dim3(1024), 0, stream>>>(
        W, x, wsumT, xsum, xstride);
    out_kernel<<<dim3((TILES * 64 + 255) / 256), dim3(256), 0, stream>>>(
        cs, wsumT, xsum, xstride, out);
}